// Round 1
// baseline (984.950 us; speedup 1.0000x reference)
//
#include <hip/hip_runtime.h>

// GCN layer: support = X@W ; out = relu(scatter_add(vals * support[cols], rows) + bias)
// N_NODES=65536, N_EDGES=1048576, IN_F=OUT_F=64, all fp32.

#define NF 64

// ---------------------------------------------------------------------------
// Kernel 1: support = X @ W   (fp32, vector ALU; W + X tiles staged in LDS)
// Block = 256 threads. Each thread computes a float4 of outputs (16 col-groups
// x 16 rows per pass). Each block covers 64 rows (4 passes).
// ---------------------------------------------------------------------------
__global__ __launch_bounds__(256) void gemm_support(
    const float* __restrict__ X, const float* __restrict__ W,
    float* __restrict__ S)
{
    __shared__ float ws[64][64];   // W, row-major [k][c]
    __shared__ float xs[16][68];   // X tile, padded 64->68 to break bank conflicts

    // Load W (4096 floats) cooperatively as float4
    {
        const float4* W4 = (const float4*)W;
        float4* ws4 = (float4*)&ws[0][0];
        for (int i = threadIdx.x; i < 1024; i += 256) ws4[i] = W4[i];
    }
    __syncthreads();

    const int c4 = threadIdx.x & 15;   // column group (4 cols)
    const int lr = threadIdx.x >> 4;   // local row 0..15
    const int base_row = blockIdx.x * 64;

    for (int pass = 0; pass < 4; ++pass) {
        const int row0 = base_row + pass * 16;
        // Stage 16 rows of X: 256 float4s, one per thread (coalesced)
        {
            const int r  = threadIdx.x >> 4;
            const int cq = threadIdx.x & 15;
            float4 v = ((const float4*)(X + (size_t)(row0 + r) * NF))[cq];
            *(float4*)&xs[r][cq * 4] = v;
        }
        __syncthreads();

        float4 acc = {0.f, 0.f, 0.f, 0.f};
        #pragma unroll
        for (int k = 0; k < 64; ++k) {
            const float  x = xs[lr][k];
            const float4 w = *(const float4*)&ws[k][c4 * 4];
            acc.x += x * w.x; acc.y += x * w.y;
            acc.z += x * w.z; acc.w += x * w.w;
        }
        ((float4*)(S + (size_t)(row0 + lr) * NF))[c4] = acc;
        __syncthreads();
    }
}

// ---------------------------------------------------------------------------
// Kernel 2: out[n][f] = bias[f]   (out is re-poisoned to 0xAA before each call)
// ---------------------------------------------------------------------------
__global__ __launch_bounds__(256) void init_bias(
    float* __restrict__ out, const float* __restrict__ bias, int n4)
{
    int i = blockIdx.x * 256 + threadIdx.x;
    if (i < n4) {
        ((float4*)out)[i] = ((const float4*)bias)[i & 15];
    }
}

// ---------------------------------------------------------------------------
// Kernel 3: scatter-add. 16 threads per edge; each thread owns a float4 slice
// of the 64-wide feature row. 4 scalar fp32 atomics per thread.
// ---------------------------------------------------------------------------
__global__ __launch_bounds__(256) void scatter_edges(
    const int* __restrict__ rows, const int* __restrict__ cols,
    const float* __restrict__ vals, const float* __restrict__ S,
    float* __restrict__ out, int n_edges)
{
    const long long gid = (long long)blockIdx.x * 256 + threadIdx.x;
    const int e = (int)(gid >> 4);
    const int q = (int)(gid & 15);
    if (e >= n_edges) return;

    const int   col = cols[e];
    const int   row = rows[e];
    const float v   = vals[e];

    const float4 s = ((const float4*)(S + (size_t)col * NF))[q];
    float* o = out + (size_t)row * NF + q * 4;
    atomicAdd(o + 0, v * s.x);
    atomicAdd(o + 1, v * s.y);
    atomicAdd(o + 2, v * s.z);
    atomicAdd(o + 3, v * s.w);
}

// ---------------------------------------------------------------------------
// Kernel 4: ReLU in place.
// ---------------------------------------------------------------------------
__global__ __launch_bounds__(256) void relu_k(float* __restrict__ out, int n4)
{
    int i = blockIdx.x * 256 + threadIdx.x;
    if (i < n4) {
        float4 v = ((float4*)out)[i];
        v.x = fmaxf(v.x, 0.f); v.y = fmaxf(v.y, 0.f);
        v.z = fmaxf(v.z, 0.f); v.w = fmaxf(v.w, 0.f);
        ((float4*)out)[i] = v;
    }
}

extern "C" void kernel_launch(void* const* d_in, const int* in_sizes, int n_in,
                              void* d_out, int out_size, void* d_ws, size_t ws_size,
                              hipStream_t stream)
{
    const float* X     = (const float*)d_in[0];
    const int*   erows = (const int*)  d_in[1];
    const int*   ecols = (const int*)  d_in[2];
    const float* evals = (const float*)d_in[3];
    const float* W     = (const float*)d_in[4];
    const float* bias  = (const float*)d_in[5];
    float*       out   = (float*)d_out;
    float*       S     = (float*)d_ws;          // support: n_nodes*64 floats (16 MB)

    const int n_nodes = in_sizes[0] / NF;
    const int n_edges = in_sizes[1];
    const int n4      = n_nodes * NF / 4;       // float4 count of output

    gemm_support<<<n_nodes / 64, 256, 0, stream>>>(X, W, S);
    init_bias<<<(n4 + 255) / 256, 256, 0, stream>>>(out, bias, n4);

    const long long sthreads = (long long)n_edges * 16;
    scatter_edges<<<(int)((sthreads + 255) / 256), 256, 0, stream>>>(
        erows, ecols, evals, S, out, n_edges);

    relu_k<<<(n4 + 255) / 256, 256, 0, stream>>>(out, n4);
}

// Round 2
// 428.533 us; speedup vs baseline: 2.2984x; 2.2984x over previous
//
#include <hip/hip_runtime.h>

// GCN layer: support = X@W ; out = relu(csr_gather(vals * support[cols]) + bias)
// N_NODES=65536, N_EDGES=1048576, IN_F=OUT_F=64, all fp32.
//
// R2: replace 64M fp32 device atomics (72 G/s ceiling, 4x write amplification)
// with counting-sort CSR build (2M int atomics) + deterministic per-row gather.

#define NF 64

// ---------------------------------------------------------------------------
// Kernel 1: support = X @ W   (fp32 vector ALU; W + X tiles staged in LDS)
// ---------------------------------------------------------------------------
__global__ __launch_bounds__(256) void gemm_support(
    const float* __restrict__ X, const float* __restrict__ W,
    float* __restrict__ S)
{
    __shared__ float ws[64][64];
    __shared__ float xs[16][68];   // pad 64->68 breaks bank conflicts

    {
        const float4* W4 = (const float4*)W;
        float4* ws4 = (float4*)&ws[0][0];
        for (int i = threadIdx.x; i < 1024; i += 256) ws4[i] = W4[i];
    }
    __syncthreads();

    const int c4 = threadIdx.x & 15;
    const int lr = threadIdx.x >> 4;
    const int base_row = blockIdx.x * 64;

    for (int pass = 0; pass < 4; ++pass) {
        const int row0 = base_row + pass * 16;
        {
            const int r  = threadIdx.x >> 4;
            const int cq = threadIdx.x & 15;
            float4 v = ((const float4*)(X + (size_t)(row0 + r) * NF))[cq];
            *(float4*)&xs[r][cq * 4] = v;
        }
        __syncthreads();

        float4 acc = {0.f, 0.f, 0.f, 0.f};
        #pragma unroll
        for (int k = 0; k < 64; ++k) {
            const float  x = xs[lr][k];
            const float4 w = *(const float4*)&ws[k][c4 * 4];
            acc.x += x * w.x; acc.y += x * w.y;
            acc.z += x * w.z; acc.w += x * w.w;
        }
        ((float4*)(S + (size_t)(row0 + lr) * NF))[c4] = acc;
        __syncthreads();
    }
}

// ---------------------------------------------------------------------------
// Kernel 2: zero the histogram (ws is poisoned 0xAA before every call)
// ---------------------------------------------------------------------------
__global__ __launch_bounds__(256) void zero_counts(int* __restrict__ counts, int n)
{
    int i = blockIdx.x * 256 + threadIdx.x;
    if (i < n) counts[i] = 0;
}

// ---------------------------------------------------------------------------
// Kernel 3: histogram of destination rows
// ---------------------------------------------------------------------------
__global__ __launch_bounds__(256) void hist_rows(
    const int* __restrict__ rows, int* __restrict__ counts, int n_edges)
{
    int i = blockIdx.x * 256 + threadIdx.x;
    if (i < n_edges) atomicAdd(&counts[rows[i]], 1);
}

// ---------------------------------------------------------------------------
// Kernel 4: exclusive scan of counts -> offsets (+ cursor copy).
// Single block, 1024 threads x 64 elements each = 65536.
// ---------------------------------------------------------------------------
__global__ __launch_bounds__(1024) void scan_offsets(
    const int* __restrict__ counts, int* __restrict__ offsets,
    int* __restrict__ cursor, int n_rows, int n_edges)
{
    __shared__ int part[1024];
    const int t = threadIdx.x;
    const int C = n_rows / 1024;          // 64
    const int base = t * C;

    int s = 0;
    #pragma unroll 4
    for (int i = 0; i < C; ++i) s += counts[base + i];
    part[t] = s;
    __syncthreads();

    // Hillis-Steele inclusive scan over 1024 partials
    for (int off = 1; off < 1024; off <<= 1) {
        int v = (t >= off) ? part[t - off] : 0;
        __syncthreads();
        part[t] += v;
        __syncthreads();
    }
    int run = (t == 0) ? 0 : part[t - 1];

    for (int i = 0; i < C; ++i) {
        offsets[base + i] = run;
        cursor[base + i]  = run;
        run += counts[base + i];
    }
    if (t == 1023) offsets[n_rows] = n_edges;
}

// ---------------------------------------------------------------------------
// Kernel 5: reorder edges into CSR order (counting-sort scatter)
// ---------------------------------------------------------------------------
__global__ __launch_bounds__(256) void build_csr(
    const int* __restrict__ rows, const int* __restrict__ cols,
    const float* __restrict__ vals, int* __restrict__ cursor,
    int* __restrict__ scol, float* __restrict__ sval, int n_edges)
{
    int i = blockIdx.x * 256 + threadIdx.x;
    if (i < n_edges) {
        int r = rows[i];
        int p = atomicAdd(&cursor[r], 1);
        scol[p] = cols[i];
        sval[p] = vals[i];
    }
}

// ---------------------------------------------------------------------------
// Kernel 6: per-row gather-accumulate, fused bias + ReLU.
// One 64-lane wave per destination row; lane = feature index.
// ---------------------------------------------------------------------------
__global__ __launch_bounds__(256) void gather_rows(
    const int* __restrict__ offsets, const int* __restrict__ scol,
    const float* __restrict__ sval, const float* __restrict__ S,
    const float* __restrict__ bias, float* __restrict__ out, int n_rows)
{
    const int row  = (blockIdx.x * 256 + threadIdx.x) >> 6;
    const int lane = threadIdx.x & 63;
    if (row >= n_rows) return;

    const int beg = offsets[row];
    const int end = offsets[row + 1];
    float acc = bias[lane];

    int j = beg;
    if (j < end) {
        // software-pipeline the wave-uniform (col,val) loads
        int   c = scol[j];
        float v = sval[j];
        for (++j; j < end; ++j) {
            int   cn = scol[j];
            float vn = sval[j];
            acc += v * S[(size_t)c * NF + lane];
            c = cn; v = vn;
        }
        acc += v * S[(size_t)c * NF + lane];
    }
    out[(size_t)row * NF + lane] = fmaxf(acc, 0.f);
}

extern "C" void kernel_launch(void* const* d_in, const int* in_sizes, int n_in,
                              void* d_out, int out_size, void* d_ws, size_t ws_size,
                              hipStream_t stream)
{
    const float* X     = (const float*)d_in[0];
    const int*   erows = (const int*)  d_in[1];
    const int*   ecols = (const int*)  d_in[2];
    const float* evals = (const float*)d_in[3];
    const float* W     = (const float*)d_in[4];
    const float* bias  = (const float*)d_in[5];
    float*       out   = (float*)d_out;

    const int n_nodes = in_sizes[0] / NF;
    const int n_edges = in_sizes[1];

    // workspace layout (bytes)
    char* ws = (char*)d_ws;
    float* S       = (float*)(ws);                                   // 16 MB
    int*   counts  = (int*)  (ws + (size_t)n_nodes * NF * 4);        // 256 KB
    int*   offsets = (int*)  ((char*)counts  + (size_t)n_nodes * 4); // 256 KB + 4
    int*   cursor  = (int*)  ((char*)offsets + (size_t)(n_nodes + 16) * 4);
    int*   scol    = (int*)  ((char*)cursor  + (size_t)n_nodes * 4); // 4 MB
    float* sval    = (float*)((char*)scol    + (size_t)n_edges * 4); // 4 MB

    const int eb = (n_edges + 255) / 256;
    const int nb = (n_nodes + 255) / 256;

    gemm_support<<<n_nodes / 64, 256, 0, stream>>>(X, W, S);
    zero_counts <<<nb, 256, 0, stream>>>(counts, n_nodes);
    hist_rows   <<<eb, 256, 0, stream>>>(erows, counts, n_edges);
    scan_offsets<<<1, 1024, 0, stream>>>(counts, offsets, cursor, n_nodes, n_edges);
    build_csr   <<<eb, 256, 0, stream>>>(erows, ecols, evals, cursor, scol, sval, n_edges);
    gather_rows <<<(n_nodes * 64 + 255) / 256, 256, 0, stream>>>(
        offsets, scol, sval, S, bias, out, n_nodes);
}

// Round 3
// 301.672 us; speedup vs baseline: 3.2650x; 1.4205x over previous
//
#include <hip/hip_runtime.h>

// GCN layer: support = X@W ; out = relu(csr_gather(vals * support[cols]) + bias)
// N_NODES=65536, N_EDGES=1048576, IN_F=OUT_F=64, all fp32.
//
// R2: counting-sort CSR + deterministic per-row gather (replaced 64M fp32 atomics).
// R3: replace 135us single-block scan (0.14% occupancy) with 2-kernel wide scan.

#define NF 64

// ---------------------------------------------------------------------------
// Kernel 1: support = X @ W   (fp32 vector ALU; W + X tiles staged in LDS)
// ---------------------------------------------------------------------------
__global__ __launch_bounds__(256) void gemm_support(
    const float* __restrict__ X, const float* __restrict__ W,
    float* __restrict__ S)
{
    __shared__ float ws[64][64];
    __shared__ float xs[16][68];   // pad 64->68 breaks bank conflicts

    {
        const float4* W4 = (const float4*)W;
        float4* ws4 = (float4*)&ws[0][0];
        for (int i = threadIdx.x; i < 1024; i += 256) ws4[i] = W4[i];
    }
    __syncthreads();

    const int c4 = threadIdx.x & 15;
    const int lr = threadIdx.x >> 4;
    const int base_row = blockIdx.x * 64;

    for (int pass = 0; pass < 4; ++pass) {
        const int row0 = base_row + pass * 16;
        {
            const int r  = threadIdx.x >> 4;
            const int cq = threadIdx.x & 15;
            float4 v = ((const float4*)(X + (size_t)(row0 + r) * NF))[cq];
            *(float4*)&xs[r][cq * 4] = v;
        }
        __syncthreads();

        float4 acc = {0.f, 0.f, 0.f, 0.f};
        #pragma unroll
        for (int k = 0; k < 64; ++k) {
            const float  x = xs[lr][k];
            const float4 w = *(const float4*)&ws[k][c4 * 4];
            acc.x += x * w.x; acc.y += x * w.y;
            acc.z += x * w.z; acc.w += x * w.w;
        }
        ((float4*)(S + (size_t)(row0 + lr) * NF))[c4] = acc;
        __syncthreads();
    }
}

// ---------------------------------------------------------------------------
// Kernel 2: zero the histogram (ws is poisoned 0xAA before every call)
// ---------------------------------------------------------------------------
__global__ __launch_bounds__(256) void zero_counts(int* __restrict__ counts, int n)
{
    int i = blockIdx.x * 256 + threadIdx.x;
    if (i < n) counts[i] = 0;
}

// ---------------------------------------------------------------------------
// Kernel 3: histogram of destination rows
// ---------------------------------------------------------------------------
__global__ __launch_bounds__(256) void hist_rows(
    const int* __restrict__ rows, int* __restrict__ counts, int n_edges)
{
    int i = blockIdx.x * 256 + threadIdx.x;
    if (i < n_edges) atomicAdd(&counts[rows[i]], 1);
}

// ---------------------------------------------------------------------------
// Kernel 4a: per-block exclusive scan of counts (256 elems/block).
// Writes block-local exclusive values to offsets, block total to blocksum.
// ---------------------------------------------------------------------------
__global__ __launch_bounds__(256) void scan_blk(
    const int* __restrict__ counts, int* __restrict__ offsets,
    int* __restrict__ blocksum)
{
    __shared__ int sh[256];
    const int t = threadIdx.x;
    const int i = blockIdx.x * 256 + t;
    const int v = counts[i];
    sh[t] = v;
    __syncthreads();
    for (int off = 1; off < 256; off <<= 1) {
        int u = (t >= off) ? sh[t - off] : 0;
        __syncthreads();
        sh[t] += u;
        __syncthreads();
    }
    offsets[i] = sh[t] - v;                      // block-local exclusive
    if (t == 255) blocksum[blockIdx.x] = sh[255];
}

// ---------------------------------------------------------------------------
// Kernel 4b: add scanned block bases in place; mirror into cursor.
// Each block redundantly scans the 256 block sums in LDS (cheap).
// ---------------------------------------------------------------------------
__global__ __launch_bounds__(256) void scan_apply(
    const int* __restrict__ blocksum, int* __restrict__ offsets,
    int* __restrict__ cursor, int n_rows, int n_edges)
{
    __shared__ int sh[256];
    const int t = threadIdx.x;
    const int b = blockIdx.x;
    sh[t] = blocksum[t];
    __syncthreads();
    for (int off = 1; off < 256; off <<= 1) {
        int u = (t >= off) ? sh[t - off] : 0;
        __syncthreads();
        sh[t] += u;
        __syncthreads();
    }
    const int base = (b == 0) ? 0 : sh[b - 1];
    const int i = b * 256 + t;
    const int v = offsets[i] + base;
    offsets[i] = v;
    cursor[i]  = v;
    if (b == 255 && t == 255) offsets[n_rows] = n_edges;
}

// ---------------------------------------------------------------------------
// Kernel 5: reorder edges into CSR order (counting-sort scatter)
// ---------------------------------------------------------------------------
__global__ __launch_bounds__(256) void build_csr(
    const int* __restrict__ rows, const int* __restrict__ cols,
    const float* __restrict__ vals, int* __restrict__ cursor,
    int* __restrict__ scol, float* __restrict__ sval, int n_edges)
{
    int i = blockIdx.x * 256 + threadIdx.x;
    if (i < n_edges) {
        int r = rows[i];
        int p = atomicAdd(&cursor[r], 1);
        scol[p] = cols[i];
        sval[p] = vals[i];
    }
}

// ---------------------------------------------------------------------------
// Kernel 6: per-row gather-accumulate, fused bias + ReLU.
// One 64-lane wave per destination row; lane = feature index.
// ---------------------------------------------------------------------------
__global__ __launch_bounds__(256) void gather_rows(
    const int* __restrict__ offsets, const int* __restrict__ scol,
    const float* __restrict__ sval, const float* __restrict__ S,
    const float* __restrict__ bias, float* __restrict__ out, int n_rows)
{
    const int row  = (blockIdx.x * 256 + threadIdx.x) >> 6;
    const int lane = threadIdx.x & 63;
    if (row >= n_rows) return;

    const int beg = offsets[row];
    const int end = offsets[row + 1];
    float acc = bias[lane];

    int j = beg;
    if (j < end) {
        int   c = scol[j];
        float v = sval[j];
        for (++j; j < end; ++j) {
            int   cn = scol[j];
            float vn = sval[j];
            acc += v * S[(size_t)c * NF + lane];
            c = cn; v = vn;
        }
        acc += v * S[(size_t)c * NF + lane];
    }
    out[(size_t)row * NF + lane] = fmaxf(acc, 0.f);
}

extern "C" void kernel_launch(void* const* d_in, const int* in_sizes, int n_in,
                              void* d_out, int out_size, void* d_ws, size_t ws_size,
                              hipStream_t stream)
{
    const float* X     = (const float*)d_in[0];
    const int*   erows = (const int*)  d_in[1];
    const int*   ecols = (const int*)  d_in[2];
    const float* evals = (const float*)d_in[3];
    const float* W     = (const float*)d_in[4];
    const float* bias  = (const float*)d_in[5];
    float*       out   = (float*)d_out;

    const int n_nodes = in_sizes[0] / NF;
    const int n_edges = in_sizes[1];

    // workspace layout
    char* ws = (char*)d_ws;
    float* S        = (float*)(ws);                                    // 16 MB
    int*   counts   = (int*)  (ws + (size_t)n_nodes * NF * 4);         // 256 KB
    int*   offsets  = (int*)  ((char*)counts   + (size_t)n_nodes * 4); // 256 KB + pad
    int*   cursor   = (int*)  ((char*)offsets  + (size_t)(n_nodes + 16) * 4);
    int*   blocksum = (int*)  ((char*)cursor   + (size_t)n_nodes * 4); // 1 KB
    int*   scol     = (int*)  ((char*)blocksum + 4096);                // 4 MB
    float* sval     = (float*)((char*)scol     + (size_t)n_edges * 4); // 4 MB

    const int eb = (n_edges + 255) / 256;
    const int nb = (n_nodes + 255) / 256;
    const int sb = n_nodes / 256;    // 256 scan blocks

    gemm_support<<<n_nodes / 64, 256, 0, stream>>>(X, W, S);
    zero_counts <<<nb, 256, 0, stream>>>(counts, n_nodes);
    hist_rows   <<<eb, 256, 0, stream>>>(erows, counts, n_edges);
    scan_blk    <<<sb, 256, 0, stream>>>(counts, offsets, blocksum);
    scan_apply  <<<sb, 256, 0, stream>>>(blocksum, offsets, cursor, n_nodes, n_edges);
    build_csr   <<<eb, 256, 0, stream>>>(erows, ecols, evals, cursor, scol, sval, n_edges);
    gather_rows <<<(n_nodes * 64 + 255) / 256, 256, 0, stream>>>(
        offsets, scol, sval, S, bias, out, n_nodes);
}

// Round 4
// 246.127 us; speedup vs baseline: 4.0018x; 1.2257x over previous
//
#include <hip/hip_runtime.h>

// GCN layer: support = X@W ; out = relu(csr_gather(vals * support[cols]) + bias)
// N_NODES=65536, N_EDGES=1048576, IN_F=OUT_F=64, all fp32.
//
// R2: counting-sort CSR + per-row gather (replaced 64M fp32 atomics).
// R3: wide 2-kernel scan (was 135us single-block).
// R4: gather unrolled x4 (4 outstanding S-loads/wave, was latency-bound at
//     2.9 TB/s logical), CSR edges packed int2 (1 random store/edge not 2),
//     hipMemsetAsync for histogram zero.

#define NF 64

// ---------------------------------------------------------------------------
// Kernel 1: support = X @ W   (fp32 vector ALU; W + X tiles staged in LDS)
// ---------------------------------------------------------------------------
__global__ __launch_bounds__(256) void gemm_support(
    const float* __restrict__ X, const float* __restrict__ W,
    float* __restrict__ S)
{
    __shared__ float ws[64][64];
    __shared__ float xs[16][68];   // pad 64->68 breaks bank conflicts

    {
        const float4* W4 = (const float4*)W;
        float4* ws4 = (float4*)&ws[0][0];
        for (int i = threadIdx.x; i < 1024; i += 256) ws4[i] = W4[i];
    }
    __syncthreads();

    const int c4 = threadIdx.x & 15;
    const int lr = threadIdx.x >> 4;
    const int base_row = blockIdx.x * 64;

    for (int pass = 0; pass < 4; ++pass) {
        const int row0 = base_row + pass * 16;
        {
            const int r  = threadIdx.x >> 4;
            const int cq = threadIdx.x & 15;
            float4 v = ((const float4*)(X + (size_t)(row0 + r) * NF))[cq];
            *(float4*)&xs[r][cq * 4] = v;
        }
        __syncthreads();

        float4 acc = {0.f, 0.f, 0.f, 0.f};
        #pragma unroll
        for (int k = 0; k < 64; ++k) {
            const float  x = xs[lr][k];
            const float4 w = *(const float4*)&ws[k][c4 * 4];
            acc.x += x * w.x; acc.y += x * w.y;
            acc.z += x * w.z; acc.w += x * w.w;
        }
        ((float4*)(S + (size_t)(row0 + lr) * NF))[c4] = acc;
        __syncthreads();
    }
}

// ---------------------------------------------------------------------------
// Kernel 2: histogram of destination rows (counts zeroed via memset)
// ---------------------------------------------------------------------------
__global__ __launch_bounds__(256) void hist_rows(
    const int* __restrict__ rows, int* __restrict__ counts, int n_edges)
{
    int i = blockIdx.x * 256 + threadIdx.x;
    if (i < n_edges) atomicAdd(&counts[rows[i]], 1);
}

// ---------------------------------------------------------------------------
// Kernel 3a: per-block exclusive scan of counts (256 elems/block).
// ---------------------------------------------------------------------------
__global__ __launch_bounds__(256) void scan_blk(
    const int* __restrict__ counts, int* __restrict__ offsets,
    int* __restrict__ blocksum)
{
    __shared__ int sh[256];
    const int t = threadIdx.x;
    const int i = blockIdx.x * 256 + t;
    const int v = counts[i];
    sh[t] = v;
    __syncthreads();
    for (int off = 1; off < 256; off <<= 1) {
        int u = (t >= off) ? sh[t - off] : 0;
        __syncthreads();
        sh[t] += u;
        __syncthreads();
    }
    offsets[i] = sh[t] - v;
    if (t == 255) blocksum[blockIdx.x] = sh[255];
}

// ---------------------------------------------------------------------------
// Kernel 3b: add scanned block bases in place; mirror into cursor.
// ---------------------------------------------------------------------------
__global__ __launch_bounds__(256) void scan_apply(
    const int* __restrict__ blocksum, int* __restrict__ offsets,
    int* __restrict__ cursor, int n_rows, int n_edges)
{
    __shared__ int sh[256];
    const int t = threadIdx.x;
    const int b = blockIdx.x;
    sh[t] = blocksum[t];
    __syncthreads();
    for (int off = 1; off < 256; off <<= 1) {
        int u = (t >= off) ? sh[t - off] : 0;
        __syncthreads();
        sh[t] += u;
        __syncthreads();
    }
    const int base = (b == 0) ? 0 : sh[b - 1];
    const int i = b * 256 + t;
    const int v = offsets[i] + base;
    offsets[i] = v;
    cursor[i]  = v;
    if (b == 255 && t == 255) offsets[n_rows] = n_edges;
}

// ---------------------------------------------------------------------------
// Kernel 4: reorder edges into CSR order; packed (col, val) int2 per edge
// so the random scatter touches ONE cache line per edge, not two.
// ---------------------------------------------------------------------------
__global__ __launch_bounds__(256) void build_csr(
    const int* __restrict__ rows, const int* __restrict__ cols,
    const float* __restrict__ vals, int* __restrict__ cursor,
    int2* __restrict__ spack, int n_edges)
{
    int i = blockIdx.x * 256 + threadIdx.x;
    if (i < n_edges) {
        int r = rows[i];
        int p = atomicAdd(&cursor[r], 1);
        spack[p] = make_int2(cols[i], __float_as_int(vals[i]));
    }
}

// ---------------------------------------------------------------------------
// Kernel 5: per-row gather-accumulate, fused bias + ReLU.
// One 64-lane wave per destination row; lane = feature index.
// Unrolled x4: 4 independent accumulators -> 4 outstanding S-row loads.
// ---------------------------------------------------------------------------
__global__ __launch_bounds__(256) void gather_rows(
    const int* __restrict__ offsets, const int2* __restrict__ spack,
    const float* __restrict__ S, const float* __restrict__ bias,
    float* __restrict__ out, int n_rows)
{
    const int row  = (blockIdx.x * 256 + threadIdx.x) >> 6;
    const int lane = threadIdx.x & 63;
    if (row >= n_rows) return;

    // wave-uniform segment bounds -> SGPRs (steers edge stream to s_load)
    const int beg = __builtin_amdgcn_readfirstlane(offsets[row]);
    const int end = __builtin_amdgcn_readfirstlane(offsets[row + 1]);

    float a0 = 0.f, a1 = 0.f, a2 = 0.f, a3 = 0.f;
    int j = beg;
    for (; j + 4 <= end; j += 4) {
        const int2 e0 = spack[j + 0];
        const int2 e1 = spack[j + 1];
        const int2 e2 = spack[j + 2];
        const int2 e3 = spack[j + 3];
        a0 += __int_as_float(e0.y) * S[(size_t)e0.x * NF + lane];
        a1 += __int_as_float(e1.y) * S[(size_t)e1.x * NF + lane];
        a2 += __int_as_float(e2.y) * S[(size_t)e2.x * NF + lane];
        a3 += __int_as_float(e3.y) * S[(size_t)e3.x * NF + lane];
    }
    for (; j < end; ++j) {
        const int2 e = spack[j];
        a0 += __int_as_float(e.y) * S[(size_t)e.x * NF + lane];
    }
    const float acc = bias[lane] + ((a0 + a1) + (a2 + a3));
    out[(size_t)row * NF + lane] = fmaxf(acc, 0.f);
}

extern "C" void kernel_launch(void* const* d_in, const int* in_sizes, int n_in,
                              void* d_out, int out_size, void* d_ws, size_t ws_size,
                              hipStream_t stream)
{
    const float* X     = (const float*)d_in[0];
    const int*   erows = (const int*)  d_in[1];
    const int*   ecols = (const int*)  d_in[2];
    const float* evals = (const float*)d_in[3];
    const float* W     = (const float*)d_in[4];
    const float* bias  = (const float*)d_in[5];
    float*       out   = (float*)d_out;

    const int n_nodes = in_sizes[0] / NF;
    const int n_edges = in_sizes[1];

    // workspace layout
    char* ws = (char*)d_ws;
    float* S        = (float*)(ws);                                    // 16 MB
    int*   counts   = (int*)  (ws + (size_t)n_nodes * NF * 4);         // 256 KB
    int*   offsets  = (int*)  ((char*)counts   + (size_t)n_nodes * 4); // 256 KB + pad
    int*   cursor   = (int*)  ((char*)offsets  + (size_t)(n_nodes + 16) * 4);
    int*   blocksum = (int*)  ((char*)cursor   + (size_t)n_nodes * 4); // 1 KB
    int2*  spack    = (int2*) ((char*)blocksum + 4096);                // 8 MB

    const int eb = (n_edges + 255) / 256;
    const int sb = n_nodes / 256;    // 256 scan blocks

    gemm_support<<<n_nodes / 64, 256, 0, stream>>>(X, W, S);
    hipMemsetAsync(counts, 0, (size_t)n_nodes * 4, stream);
    hist_rows   <<<eb, 256, 0, stream>>>(erows, counts, n_edges);
    scan_blk    <<<sb, 256, 0, stream>>>(counts, offsets, blocksum);
    scan_apply  <<<sb, 256, 0, stream>>>(blocksum, offsets, cursor, n_nodes, n_edges);
    build_csr   <<<eb, 256, 0, stream>>>(erows, ecols, evals, cursor, spack, n_edges);
    gather_rows <<<(n_nodes * 64 + 255) / 256, 256, 0, stream>>>(
        offsets, spack, S, bias, out, n_nodes);
}

// Round 5
// 169.060 us; speedup vs baseline: 5.8260x; 1.4559x over previous
//
#include <hip/hip_runtime.h>

// GCN layer: support = X@W ; out = relu(csr_gather(vals * support[cols]) + bias)
// N_NODES=65536, N_EDGES=1048576, IN_F=OUT_F=64, all fp32.
//
// R2: counting-sort CSR + per-row gather (replaced 64M fp32 atomics).
// R3: wide 2-kernel scan (was 135us single-block).
// R4: gather unrolled x4; packed int2 CSR edges.
// R5: two-level bucket sort for CSR build. Old build_csr had WRITE_SIZE 67MB
//     for 8MB payload (random 8B stores, cross-XCD partial-line writebacks) +
//     1M global atomics. Now: LDS-histogram buckets (row>>7), block-private
//     staged runs, per-bucket LDS-cursor scatter into contiguous spack regions.
//     bucket_to_csr also emits offsets[], deleting hist_rows + 64K scan.

#define NF    64
#define NBKT  512      // row buckets; shift = log2(n_nodes/NBKT) = 7
#define CHUNK 4096     // edges per phase-A block

// ---------------------------------------------------------------------------
// Kernel 1: support = X @ W   (fp32 vector ALU; W + X tiles staged in LDS)
// ---------------------------------------------------------------------------
__global__ __launch_bounds__(256) void gemm_support(
    const float* __restrict__ X, const float* __restrict__ W,
    float* __restrict__ S)
{
    __shared__ float ws[64][64];
    __shared__ float xs[16][68];   // pad 64->68 breaks bank conflicts

    {
        const float4* W4 = (const float4*)W;
        float4* ws4 = (float4*)&ws[0][0];
        for (int i = threadIdx.x; i < 1024; i += 256) ws4[i] = W4[i];
    }
    __syncthreads();

    const int c4 = threadIdx.x & 15;
    const int lr = threadIdx.x >> 4;
    const int base_row = blockIdx.x * 64;

    for (int pass = 0; pass < 4; ++pass) {
        const int row0 = base_row + pass * 16;
        {
            const int r  = threadIdx.x >> 4;
            const int cq = threadIdx.x & 15;
            float4 v = ((const float4*)(X + (size_t)(row0 + r) * NF))[cq];
            *(float4*)&xs[r][cq * 4] = v;
        }
        __syncthreads();

        float4 acc = {0.f, 0.f, 0.f, 0.f};
        #pragma unroll
        for (int k = 0; k < 64; ++k) {
            const float  x = xs[lr][k];
            const float4 w = *(const float4*)&ws[k][c4 * 4];
            acc.x += x * w.x; acc.y += x * w.y;
            acc.z += x * w.z; acc.w += x * w.w;
        }
        ((float4*)(S + (size_t)(row0 + lr) * NF))[c4] = acc;
        __syncthreads();
    }
}

// ---------------------------------------------------------------------------
// Kernel 2: per-chunk LDS histogram of 512 row-buckets -> global bucket counts
// ---------------------------------------------------------------------------
__global__ __launch_bounds__(512) void bucket_hist(
    const int* __restrict__ rows, int* __restrict__ bucket_counts,
    int n_edges, int shift)
{
    __shared__ int hist[NBKT];
    const int t = threadIdx.x;
    hist[t] = 0;
    __syncthreads();
    const int base = blockIdx.x * CHUNK;
    const int lim  = min(CHUNK, n_edges - base);
    for (int i = t; i < lim; i += 512)
        atomicAdd(&hist[((unsigned)rows[base + i]) >> shift], 1);
    __syncthreads();
    if (hist[t]) atomicAdd(&bucket_counts[t], hist[t]);
}

// ---------------------------------------------------------------------------
// Kernel 3: scan 512 bucket counts -> bucketbase + cursor init (single block)
// ---------------------------------------------------------------------------
__global__ __launch_bounds__(512) void scan_buckets(
    const int* __restrict__ bucket_counts, int* __restrict__ bucketbase,
    int* __restrict__ bucket_cursor, int* __restrict__ offsets,
    int n_edges, int n_nodes)
{
    __shared__ int sh[NBKT];
    const int t = threadIdx.x;
    const int v = bucket_counts[t];
    sh[t] = v;
    __syncthreads();
    for (int off = 1; off < NBKT; off <<= 1) {
        int u = (t >= off) ? sh[t - off] : 0;
        __syncthreads();
        sh[t] += u;
        __syncthreads();
    }
    const int excl = sh[t] - v;
    bucketbase[t]   = excl;
    bucket_cursor[t] = excl;
    if (t == NBKT - 1) { bucketbase[NBKT] = n_edges; offsets[n_nodes] = n_edges; }
}

// ---------------------------------------------------------------------------
// Kernel 4: bin each chunk into bucket runs. LDS cursors; ONE global atomic
// per (block,bucket) reservation; packed 8B edges into block-private runs.
// ---------------------------------------------------------------------------
__global__ __launch_bounds__(512) void bucket_scatter(
    const int* __restrict__ rows, const int* __restrict__ cols,
    const float* __restrict__ vals, int* __restrict__ bucket_cursor,
    int2* __restrict__ staged, int n_edges, int shift)
{
    __shared__ int hist[NBKT];
    __shared__ int cur[NBKT];
    __shared__ int lrow[CHUNK];
    const int t = threadIdx.x;
    hist[t] = 0;
    __syncthreads();
    const int base = blockIdx.x * CHUNK;
    const int lim  = min(CHUNK, n_edges - base);
    for (int i = t; i < lim; i += 512) {
        int r = rows[base + i];
        lrow[i] = r;
        atomicAdd(&hist[((unsigned)r) >> shift], 1);
    }
    __syncthreads();
    cur[t] = hist[t] ? atomicAdd(&bucket_cursor[t], hist[t]) : 0;
    __syncthreads();
    for (int i = t; i < lim; i += 512) {
        int r = lrow[i];
        int b = ((unsigned)r) >> shift;
        int p = atomicAdd(&cur[b], 1);
        staged[p] = make_int2((int)(((unsigned)r << 16) | (unsigned)cols[base + i]),
                              __float_as_int(vals[base + i]));
    }
}

// ---------------------------------------------------------------------------
// Kernel 5: one block per bucket: LDS row-histogram -> LDS scan -> write
// offsets[] -> LDS-cursor scatter into the bucket's contiguous spack region.
// ---------------------------------------------------------------------------
__global__ __launch_bounds__(256) void bucket_to_csr(
    const int* __restrict__ bucketbase, const int2* __restrict__ staged,
    int* __restrict__ offsets, int2* __restrict__ spack, int rows_per_bkt)
{
    __shared__ int hist[128];
    __shared__ int cur[128];
    const int k = blockIdx.x;
    const int t = threadIdx.x;
    const int base = bucketbase[k];
    const int end  = bucketbase[k + 1];
    const int mask = rows_per_bkt - 1;

    if (t < rows_per_bkt) hist[t] = 0;
    __syncthreads();
    for (int i = base + t; i < end; i += 256)
        atomicAdd(&hist[(((unsigned)staged[i].x) >> 16) & mask], 1);
    __syncthreads();

    const int v = (t < rows_per_bkt) ? hist[t] : 0;
    for (int off = 1; off < 128; off <<= 1) {
        int u = (t < rows_per_bkt && t >= off) ? hist[t - off] : 0;
        __syncthreads();
        if (t < rows_per_bkt) hist[t] += u;
        __syncthreads();
    }
    if (t < rows_per_bkt) {
        const int pos = base + hist[t] - v;     // exclusive
        offsets[k * rows_per_bkt + t] = pos;
        cur[t] = pos;
    }
    __syncthreads();
    for (int i = base + t; i < end; i += 256) {
        int2 e = staged[i];
        int r = (((unsigned)e.x) >> 16) & mask;
        int p = atomicAdd(&cur[r], 1);
        spack[p] = make_int2(e.x & 0xFFFF, e.y);
    }
}

// ---------------------------------------------------------------------------
// Kernel 6: per-row gather-accumulate, fused bias + ReLU.
// One 64-lane wave per destination row; unrolled x4 for MLP.
// ---------------------------------------------------------------------------
__global__ __launch_bounds__(256) void gather_rows(
    const int* __restrict__ offsets, const int2* __restrict__ spack,
    const float* __restrict__ S, const float* __restrict__ bias,
    float* __restrict__ out, int n_rows)
{
    const int row  = (blockIdx.x * 256 + threadIdx.x) >> 6;
    const int lane = threadIdx.x & 63;
    if (row >= n_rows) return;

    const int beg = __builtin_amdgcn_readfirstlane(offsets[row]);
    const int end = __builtin_amdgcn_readfirstlane(offsets[row + 1]);

    float a0 = 0.f, a1 = 0.f, a2 = 0.f, a3 = 0.f;
    int j = beg;
    for (; j + 4 <= end; j += 4) {
        const int2 e0 = spack[j + 0];
        const int2 e1 = spack[j + 1];
        const int2 e2 = spack[j + 2];
        const int2 e3 = spack[j + 3];
        a0 += __int_as_float(e0.y) * S[(size_t)e0.x * NF + lane];
        a1 += __int_as_float(e1.y) * S[(size_t)e1.x * NF + lane];
        a2 += __int_as_float(e2.y) * S[(size_t)e2.x * NF + lane];
        a3 += __int_as_float(e3.y) * S[(size_t)e3.x * NF + lane];
    }
    for (; j < end; ++j) {
        const int2 e = spack[j];
        a0 += __int_as_float(e.y) * S[(size_t)e.x * NF + lane];
    }
    const float acc = bias[lane] + ((a0 + a1) + (a2 + a3));
    out[(size_t)row * NF + lane] = fmaxf(acc, 0.f);
}

extern "C" void kernel_launch(void* const* d_in, const int* in_sizes, int n_in,
                              void* d_out, int out_size, void* d_ws, size_t ws_size,
                              hipStream_t stream)
{
    const float* X     = (const float*)d_in[0];
    const int*   erows = (const int*)  d_in[1];
    const int*   ecols = (const int*)  d_in[2];
    const float* evals = (const float*)d_in[3];
    const float* W     = (const float*)d_in[4];
    const float* bias  = (const float*)d_in[5];
    float*       out   = (float*)d_out;

    const int n_nodes = in_sizes[0] / NF;
    const int n_edges = in_sizes[1];
    const int rows_per_bkt = n_nodes / NBKT;        // 128
    int shift = 0; while ((NBKT << shift) < n_nodes) ++shift;   // 7

    // workspace layout (16B-aligned chunks)
    char* ws = (char*)d_ws;
    float* S             = (float*)(ws);                                  // 16 MB
    int2*  staged        = (int2*) (ws + (size_t)n_nodes * NF * 4);       // 8 MB
    int2*  spack         = (int2*) ((char*)staged + (size_t)n_edges * 8); // 8 MB
    int*   offsets       = (int*)  ((char*)spack  + (size_t)n_edges * 8); // 256 KB
    int*   bucket_counts = (int*)  ((char*)offsets + (size_t)(n_nodes + 4) * 4);
    int*   bucketbase    = (int*)  ((char*)bucket_counts + (NBKT + 4) * 4);
    int*   bucket_cursor = (int*)  ((char*)bucketbase   + (NBKT + 4) * 4);

    const int ablocks = (n_edges + CHUNK - 1) / CHUNK;   // 256

    gemm_support <<<n_nodes / 64, 256, 0, stream>>>(X, W, S);
    hipMemsetAsync(bucket_counts, 0, (size_t)NBKT * 4, stream);
    bucket_hist  <<<ablocks, 512, 0, stream>>>(erows, bucket_counts, n_edges, shift);
    scan_buckets <<<1, NBKT, 0, stream>>>(bucket_counts, bucketbase, bucket_cursor,
                                          offsets, n_edges, n_nodes);
    bucket_scatter<<<ablocks, 512, 0, stream>>>(erows, ecols, evals, bucket_cursor,
                                                staged, n_edges, shift);
    bucket_to_csr<<<NBKT, 256, 0, stream>>>(bucketbase, staged, offsets, spack,
                                            rows_per_bkt);
    gather_rows  <<<(n_nodes * 64 + 255) / 256, 256, 0, stream>>>(
        offsets, spack, S, bias, out, n_nodes);
}